// Round 1
// 7599.308 us; speedup vs baseline: 2.4237x; 2.4237x over previous
//
#include <hip/hip_runtime.h>
#include <stdint.h>

// SpikingNetwork B=128 T=128 I=1024 dims 2048/2048/1024, beta=0.9, thr=1.0.
// R5: occupancy + conflict rework. 512 blocks x 256 thr (8 waves/CU = 2/SIMD,
// double R4). Tiles 64m x 32n; each block computes TWO sequential 512-k fmac
// chains in-register (DAG identical to R4: chains split at 512 boundaries,
// merged in ascending order with plain fadd). L0: full K=1024 in-block, no
// helpers. L1/L2: ksplit2 — helper ships P2,P3 separately; owner does
// ((P0+P1)+P2)+P3. lB natural [n][k] (conflict-free staging, broadcast reads);
// lA [k][m] with XOR swizzle col = m ^ ((k&16)|((k^(k>>3))&12)) on write+read.
// done-flags per m-half (target 64). Spikes as bitmasks, agent-scope atomics.

#define TT   128
#define NB   128
#define DD2  1024

// ws layout (u32 units)
#define SPK0_OFF 0u
#define SPK1_OFF (128u*128u*64u)                 // 1,048,576
#define PART_OFF (2u*128u*128u*64u)              // 2,097,152
#define NHELP    192u
#define FLG_OFF  (PART_OFF + NHELP*4096u)        // 2,883,584
#define NFLG     1536u                           // pflag512 oflag512 done0 2x128 done1 2x128
#define WS_NEED_BYTES ((size_t)(FLG_OFF + NFLG) * 4u)   // 11,540,480

__device__ __forceinline__ void wait_ge(uint32_t* p, uint32_t tgt){
  while (__hip_atomic_load(p, __ATOMIC_ACQUIRE, __HIP_MEMORY_SCOPE_AGENT) < tgt)
    __builtin_amdgcn_s_sleep(1);
}

// LDS column swizzle for lA: keeps 4-float granules (b128-aligned), uses k bits
// 2..6 so both the 4-consecutive-k staging writes and the 32-apart expansion
// rows land on distinct banks.
__device__ __forceinline__ int fswz(int k){
  return (k & 16) | ((k ^ (k >> 3)) & 12);
}

__global__ void sentinel_kernel(float* o){ o[0] = 42.0f; }   // ws-too-small marker

__global__ __launch_bounds__(256, 2) void snn_kernel(
    const float* __restrict__ x,
    const float* __restrict__ W0, const float* __restrict__ b0,
    const float* __restrict__ W1, const float* __restrict__ b1,
    const float* __restrict__ W2, const float* __restrict__ b2,
    float* __restrict__ out, uint32_t* __restrict__ ws)
{
  __shared__ __align__(16) float lA[128][68];   // [k][m^swz], 34,816 B
  __shared__ __align__(16) float lB[32][132];   // [n][k], natural, 16,896 B
  __shared__ uint32_t lBits[64];                // one 32-bit spike word per row

  const int tid = threadIdx.x;
  const int tm  = tid & 15;      // m-group: rows tm*4 .. +3
  const int tn  = tid >> 4;      // n-group: cols tn*2 .. +1
  const int bid = blockIdx.x;

  uint32_t* spikes0  = ws + SPK0_OFF;
  uint32_t* spikes1  = ws + SPK1_OFF;
  float*    partials = (float*)(ws + PART_OFF);   // [NHELP][4096]
  uint32_t* flg   = ws + FLG_OFF;
  uint32_t* pflag = flg;            // [512] helper->owner: partials for t ready (t+1)
  uint32_t* oflag = flg + 512;      // [512] owner->helper: consumed through t (t+1)
  uint32_t* done0 = flg + 1024;     // [2][128] per m-half, target 64
  uint32_t* done1 = flg + 1280;     // [2][128]

  int group, kp, tl, m0, n0, K, hslot;
  const float *Wl, *bl;
  const uint32_t* spkIn; uint32_t* spkOut;
  uint32_t *dIn, *dOut;
  if (bid < 128) {          // L0: out 128x2048, K=1024, both halves in-block
    group=0; kp=0; tl=bid;
    m0=(tl>>6)*64; n0=(tl&63)*32; K=1024; Wl=W0; bl=b0;
    spkIn=nullptr; spkOut=spikes0; dIn=nullptr; dOut=done0 + (m0>>6)*128; hslot=-1;
  } else if (bid < 384) {   // L1: out 128x2048, K=2048, ksplit2
    group=1; int rel=bid-128; kp=rel&1; tl=rel>>1;
    m0=(tl>>6)*64; n0=(tl&63)*32; K=2048; Wl=W1; bl=b1;
    spkIn=spikes0; spkOut=spikes1;
    dIn=done0 + (m0>>6)*128; dOut=done1 + (m0>>6)*128; hslot=tl;
  } else {                  // L2: out 128x1024, K=2048, ksplit2
    group=2; int rel=bid-384; kp=rel&1; tl=rel>>1;
    m0=(tl>>5)*64; n0=(tl&31)*32; K=2048; Wl=W2; bl=b2;
    spkIn=spikes1; spkOut=nullptr;
    dIn=done1 + (m0>>6)*128; dOut=nullptr; hslot=128+tl;
  }
  const bool owner = (kp == 0);
  const int  K0    = kp * 1024;

  const float bias0 = bl[n0 + tn*2 + 0];
  const float bias1 = bl[n0 + tn*2 + 1];

  float vst[4][2];
  #pragma unroll
  for (int r = 0; r < 4; ++r) { vst[r][0] = 0.f; vst[r][1] = 0.f; }

  for (int t = 0; t < TT; ++t) {
    if (dIn) {  // previous layer's spikes for this m-half must be complete
      if (tid == 0) wait_ge(&dIn[t], 64u);
      __syncthreads();
    }

    float acc2[2][4][2];   // two 512-k partial chains (p unrolled -> static idx)
    #pragma unroll
    for (int p = 0; p < 2; ++p) {
      #pragma unroll
      for (int r = 0; r < 4; ++r) { acc2[p][r][0] = 0.f; acc2[p][r][1] = 0.f; }

      #pragma unroll 1
      for (int ch = 0; ch < 4; ++ch) {
        const int kb = K0 + p*512 + ch*128;

        // ---- stage B: weights, natural [n][k] layout (contiguous, bank-optimal)
        #pragma unroll
        for (int it = 0; it < 4; ++it) {
          int idx = tid + it*256;
          int nrow = idx >> 5, kq = idx & 31;
          float4 w = *(const float4*)(Wl + (size_t)(n0+nrow)*K + kb + kq*4);
          *(float4*)&lB[nrow][kq*4] = w;
        }

        // ---- stage A
        if (group == 0) {       // x[b,t,k] -> lA[k][m^swz]
          #pragma unroll
          for (int it = 0; it < 8; ++it) {
            int idx = tid + it*256;
            int mrow = idx >> 5, kq = idx & 31;
            float4 v = *(const float4*)(x + ((size_t)(m0+mrow)*TT + t)*1024 + kb + kq*4);
            int k0 = kq*4;
            lA[k0+0][mrow ^ fswz(k0+0)] = v.x;
            lA[k0+1][mrow ^ fswz(k0+1)] = v.y;
            lA[k0+2][mrow ^ fswz(k0+2)] = v.z;
            lA[k0+3][mrow ^ fswz(k0+3)] = v.w;
          }
        } else {                // spike bits -> {0,1} f32; 4 rows x 8 k per thread
          const int mq   = tid & 15;            // row quad mq*4..+3
          const int sub  = tid >> 4;
          const int wsub = sub & 3;             // which 32-bit word
          const int kq8  = sub >> 2;            // which 8-k slice of that word
          const size_t rb = ((size_t)t*NB + m0 + mq*4)*64 + (kb>>5) + wsub;
          uint32_t w0 = __hip_atomic_load(&spkIn[rb      ], __ATOMIC_RELAXED, __HIP_MEMORY_SCOPE_AGENT);
          uint32_t w1 = __hip_atomic_load(&spkIn[rb +  64], __ATOMIC_RELAXED, __HIP_MEMORY_SCOPE_AGENT);
          uint32_t w2 = __hip_atomic_load(&spkIn[rb + 128], __ATOMIC_RELAXED, __HIP_MEMORY_SCOPE_AGENT);
          uint32_t w3 = __hip_atomic_load(&spkIn[rb + 192], __ATOMIC_RELAXED, __HIP_MEMORY_SCOPE_AGENT);
          const int kloc = wsub*32 + kq8*8;
          #pragma unroll
          for (int i = 0; i < 8; ++i) {
            int k  = kloc + i;
            int sh = k & 31;
            float4 f;
            f.x = ((w0 >> sh) & 1u) ? 1.0f : 0.0f;
            f.y = ((w1 >> sh) & 1u) ? 1.0f : 0.0f;
            f.z = ((w2 >> sh) & 1u) ? 1.0f : 0.0f;
            f.w = ((w3 >> sh) & 1u) ? 1.0f : 0.0f;
            *(float4*)&lA[k][(mq*4) ^ fswz(k)] = f;
          }
        }
        __syncthreads();

        // ---- FMA micro-kernel: 128 k x (4m x 2n), sequential ascending k
        const float* bp0 = &lB[tn*2    ][0];
        const float* bp1 = &lB[tn*2 + 1][0];
        #pragma unroll 4
        for (int k4 = 0; k4 < 32; ++k4) {
          const int kbase = k4*4;
          const int col = (tm*4) ^ fswz(kbase);   // fswz constant over the 4 sub-ks
          #pragma unroll
          for (int u = 0; u < 4; ++u) {
            const float4 a  = *(const float4*)&lA[kbase+u][col];
            const float bv0 = bp0[kbase+u];
            const float bv1 = bp1[kbase+u];
            acc2[p][0][0] = __builtin_fmaf(a.x, bv0, acc2[p][0][0]);
            acc2[p][1][0] = __builtin_fmaf(a.y, bv0, acc2[p][1][0]);
            acc2[p][2][0] = __builtin_fmaf(a.z, bv0, acc2[p][2][0]);
            acc2[p][3][0] = __builtin_fmaf(a.w, bv0, acc2[p][3][0]);
            acc2[p][0][1] = __builtin_fmaf(a.x, bv1, acc2[p][0][1]);
            acc2[p][1][1] = __builtin_fmaf(a.y, bv1, acc2[p][1][1]);
            acc2[p][2][1] = __builtin_fmaf(a.z, bv1, acc2[p][2][1]);
            acc2[p][3][1] = __builtin_fmaf(a.w, bv1, acc2[p][3][1]);
          }
        }
        __syncthreads();
      }
    }

    if (!owner) {
      // ship P2,P3 separately (single-buffered; owner must have consumed t-1)
      if (t >= 1) { if (tid == 0) wait_ge(&oflag[bid-1], (uint32_t)t); __syncthreads(); }
      uint64_t* pb = (uint64_t*)(partials + (size_t)hslot*4096) + tid*8;
      #pragma unroll
      for (int h = 0; h < 2; ++h)
        #pragma unroll
        for (int r = 0; r < 4; ++r) {
          union { float f[2]; uint64_t u; } cv;
          cv.f[0] = acc2[h][r][0]; cv.f[1] = acc2[h][r][1];
          __hip_atomic_store(&pb[h*4+r], cv.u, __ATOMIC_RELAXED, __HIP_MEMORY_SCOPE_AGENT);
        }
      __syncthreads();
      if (tid == 0) __hip_atomic_store(&pflag[bid], (uint32_t)(t+1), __ATOMIC_RELEASE, __HIP_MEMORY_SCOPE_AGENT);
      continue;
    }

    // owner: acc = (P0 + P1), then += P2, += P3 (ascending-k merge, DAG as R4)
    float acc[4][2];
    #pragma unroll
    for (int r = 0; r < 4; ++r) {
      acc[r][0] = __fadd_rn(acc2[0][r][0], acc2[1][r][0]);
      acc[r][1] = __fadd_rn(acc2[0][r][1], acc2[1][r][1]);
    }

    if (hslot >= 0) {   // L1/L2: fold in helper's P2 then P3
      if (tid == 0) wait_ge(&pflag[bid+1], (uint32_t)(t+1));
      __syncthreads();
      uint64_t* pb = (uint64_t*)(partials + (size_t)hslot*4096) + tid*8;
      #pragma unroll
      for (int h = 0; h < 2; ++h)
        #pragma unroll
        for (int r = 0; r < 4; ++r) {
          union { uint64_t u; float f[2]; } cv;
          cv.u = __hip_atomic_load(&pb[h*4+r], __ATOMIC_RELAXED, __HIP_MEMORY_SCOPE_AGENT);
          acc[r][0] = __fadd_rn(acc[r][0], cv.f[0]);
          acc[r][1] = __fadd_rn(acc[r][1], cv.f[1]);
        }
      __syncthreads();
      if (tid == 0) __hip_atomic_store(&oflag[bid], (uint32_t)(t+1), __ATOMIC_RELEASE, __HIP_MEMORY_SCOPE_AGENT);
    }

    if (group < 2) { if (tid < 64) lBits[tid] = 0; __syncthreads(); }

    // LIF: cur = acc + b (rn); v = 0.9*v + cur (mul+add rn, NO fma contraction);
    // spk = v > 1.0 strictly; v -= spk.
    float sv[4][2], vv8[4][2];
    #pragma unroll
    for (int r = 0; r < 4; ++r) {
      uint32_t msk = 0;
      #pragma unroll
      for (int c = 0; c < 2; ++c) {
        float cur = __fadd_rn(acc[r][c], c ? bias1 : bias0);
        float vv  = __fadd_rn(__fmul_rn(0.9f, vst[r][c]), cur);
        float s   = (vv > 1.0f) ? 1.0f : 0.0f;
        vv = __fsub_rn(vv, s);
        vst[r][c] = vv;
        sv[r][c] = s; vv8[r][c] = vv;
        msk |= (s != 0.f) ? (1u << (tn*2 + c)) : 0u;
      }
      if (group < 2 && msk) atomicOr(&lBits[tm*4 + r], msk);
    }

    if (group == 2) {
      #pragma unroll
      for (int r = 0; r < 4; ++r) {
        size_t o  = ((size_t)(m0 + tm*4 + r)*TT + t)*DD2 + n0 + tn*2;
        *(float2*)(out + o)  = make_float2(sv[r][0], sv[r][1]);
        size_t ov = (size_t)NB*TT*DD2 + o;
        *(float2*)(out + ov) = make_float2(vv8[r][0], vv8[r][1]);
      }
    } else {
      __syncthreads();
      if (tid < 64)
        __hip_atomic_store(&spkOut[((size_t)t*NB + m0 + tid)*64 + (n0>>5)],
                           lBits[tid], __ATOMIC_RELAXED, __HIP_MEMORY_SCOPE_AGENT);
      __syncthreads();
      if (tid == 0) __hip_atomic_fetch_add(&dOut[t], 1u, __ATOMIC_RELEASE, __HIP_MEMORY_SCOPE_AGENT);
    }
  }
}

extern "C" void kernel_launch(void* const* d_in, const int* in_sizes, int n_in,
                              void* d_out, int out_size, void* d_ws, size_t ws_size,
                              hipStream_t stream) {
  (void)in_sizes; (void)n_in; (void)out_size;
  float* outf = (float*)d_out;
  if (ws_size < WS_NEED_BYTES) {            // diagnostic: absmax ~41 => ws too small
    sentinel_kernel<<<1, 1, 0, stream>>>(outf);
    return;
  }
  const float* x  = (const float*)d_in[0];
  const float* W0 = (const float*)d_in[1];
  const float* b0 = (const float*)d_in[2];
  const float* W1 = (const float*)d_in[3];
  const float* b1 = (const float*)d_in[4];
  const float* W2 = (const float*)d_in[5];
  const float* b2 = (const float*)d_in[6];
  uint32_t* ws = (uint32_t*)d_ws;

  // zero flags (spikes/partials are write-before-read; flags gate everything)
  hipMemsetAsync(ws + FLG_OFF, 0, NFLG * sizeof(uint32_t), stream);

  snn_kernel<<<512, 256, 0, stream>>>(x, W0, b0, W1, b1, W2, b2, outf, ws);
}